// Round 4
// baseline (2130.595 us; speedup 1.0000x reference)
//
#include <hip/hip_runtime.h>
#include <hip/hip_bf16.h>

static constexpr int TOTAL = 349525;
static constexpr int OFFS[11] = {0,1,5,21,85,341,1365,5461,21845,87381,349525};
// emb blocks of 128 nodes per level: counts {1,1,1,1,2,8,32,128,512,2048}
static constexpr int EBLK[11] = {0,1,2,3,4,6,14,46,174,686,2734};

__device__ __forceinline__ unsigned deint(unsigned v){
  v &= 0x55555555u;
  v = (v | (v>>1)) & 0x33333333u;
  v = (v | (v>>2)) & 0x0F0F0F0Fu;
  v = (v | (v>>4)) & 0x00FF00FFu;
  v = (v | (v>>8)) & 0x0000FFFFu;
  return v;
}
__device__ __forceinline__ unsigned ileave(unsigned v){
  v &= 0xFFFFu;
  v = (v | (v<<8)) & 0x00FF00FFu;
  v = (v | (v<<4)) & 0x0F0F0F0Fu;
  v = (v | (v<<2)) & 0x33333333u;
  v = (v | (v<<1)) & 0x55555555u;
  return v;
}

// ---------- in_proj: h[g] = concat(f, posenc) @ W(40x64) + b ----------
// Staging: one thread per node computes all 40 inputs (3 sincos + doubling).
__global__ __launch_bounds__(256) void k_inproj(const float* __restrict__ feat,
    const float* __restrict__ W, const float* __restrict__ B, float* __restrict__ h){
  __shared__ float Alt[128][44];   // [node][k], pitch 44 (16B aligned)
  int t = threadIdx.x;
  int base = blockIdx.x * 128;
  if (t < 128){
    int g = base + t;
    float* row = Alt[t];
    if (g < TOTAL){
      int d = 0;
      #pragma unroll
      for (int i = 1; i <= 9; ++i) if (g >= OFFS[i]) d = i;
      int local = g - OFFS[d];
      unsigned ix = deint((unsigned)local), iy = deint(((unsigned)local) >> 1);
      float inv = 1.0f / (float)(1 << d);
      float px = ((float)ix + 0.5f) * inv;
      float py = ((float)iy + 0.5f) * inv;
      float pd = (float)d * (1.0f/9.0f);
      row[0] = feat[g]; row[1] = px; row[2] = py; row[3] = pd;
      float p3[3] = {px, py, pd};
      #pragma unroll
      for (int c = 0; c < 3; ++c){
        float s, co;
        __sincosf(6.28318530717958647692f * p3[c], &s, &co);
        float* rb = row + 4 + c*12;
        #pragma unroll
        for (int f = 0; f < 6; ++f){
          rb[f] = s; rb[6+f] = co;
          float s2 = 2.f*s*co, c2 = 1.f - 2.f*s*s;
          s = s2; co = c2;
        }
      }
    } else {
      #pragma unroll
      for (int k = 0; k < 40; ++k) row[k] = 0.f;
    }
  }
  __syncthreads();
  int tr = t >> 3, tc = t & 7;        // 4 nodes x 8 ch
  float acc[4][8];
  #pragma unroll
  for (int i=0;i<4;++i)
    #pragma unroll
    for (int c=0;c<8;++c) acc[i][c] = 0.f;
  const float* Wt = W + tc*8;
  #pragma unroll
  for (int k4 = 0; k4 < 10; ++k4){
    float av[4][4];
    #pragma unroll
    for (int i=0;i<4;++i){
      float4 aa = *(const float4*)&Alt[tr*4+i][k4*4];
      av[i][0]=aa.x; av[i][1]=aa.y; av[i][2]=aa.z; av[i][3]=aa.w;
    }
    float w[4][8];
    const float* Wr = Wt + k4*256;
    #pragma unroll
    for (int j=0;j<4;++j){
      float4 lo = *(const float4*)(Wr + j*64);
      float4 hi = *(const float4*)(Wr + j*64 + 4);
      w[j][0]=lo.x; w[j][1]=lo.y; w[j][2]=lo.z; w[j][3]=lo.w;
      w[j][4]=hi.x; w[j][5]=hi.y; w[j][6]=hi.z; w[j][7]=hi.w;
    }
    #pragma unroll
    for (int i=0;i<4;++i)
      #pragma unroll
      for (int j=0;j<4;++j)
        #pragma unroll
        for (int c=0;c<8;++c) acc[i][c] += av[i][j]*w[j][c];
  }
  float bias[8];
  #pragma unroll
  for (int c=0;c<8;++c) bias[c] = B[tc*8+c];
  #pragma unroll
  for (int i=0;i<4;++i){
    int g = base + tr*4 + i;
    if (g >= TOTAL) continue;
    float ov[8];
    #pragma unroll
    for (int c=0;c<8;++c) ov[c] = acc[i][c] + bias[c];
    float* dst = &h[(size_t)g*64 + tc*8];
    *(float4*)dst       = *(const float4*)&ov[0];
    *(float4*)(dst + 4) = *(const float4*)&ov[4];
  }
}

// ---------- pool: stg[p] = h[parent p] + mean(children), float4 ----------
__global__ __launch_bounds__(256) void k_pool(const float* __restrict__ h,
    float* __restrict__ stg, int Np, int offPar, int offChild){
  int e = blockIdx.x*256 + threadIdx.x;
  if (e >= Np*16) return;
  int p = e >> 4, u = e & 15;
  const float4* c = (const float4*)(h + (size_t)(offChild + 4*p)*64) + u;
  float4 c0 = c[0], c1 = c[16], c2 = c[32], c3 = c[48];
  float4 pr = *((const float4*)(h + (size_t)(offPar + p)*64) + u);
  float4 r;
  r.x = 0.25f*(c0.x+c1.x+c2.x+c3.x) + pr.x;
  r.y = 0.25f*(c0.y+c1.y+c2.y+c3.y) + pr.y;
  r.z = 0.25f*(c0.z+c1.z+c2.z+c3.z) + pr.z;
  r.w = 0.25f*(c0.w+c1.w+c2.w+c3.w) + pr.w;
  ((float4*)stg)[e] = r;
}

// ---------- conv: h[L] = relu( gather9(stg) @ conv_W[L] + b ) ----------
// A transposed in LDS ([node][kk]); W read from global (L1-hot); T14 gather prefetch.
template<int NPB>
__global__ __launch_bounds__(256, 3) void k_conv(const float* __restrict__ A,
    const float* __restrict__ W, const float* __restrict__ Bb, float* __restrict__ h,
    int N, int off, int lbits){
  constexpr int R   = NPB/32;       // nodes per thread
  constexpr int LA4 = NPB*16/256;   // float4 gathers per thread
  __shared__ float Alt[NPB][68];    // [node][kk], pitch 68
  __shared__ unsigned short kkey[NPB][9];
  __shared__ unsigned short kmsk[NPB];
  int t = threadIdx.x;
  int nb = blockIdx.x * NPB;
  if (t < NPB){
    int node = nb + t;
    int res = 1 << lbits;
    bool ok = node < N;
    unsigned ix = 0, iy = 0;
    if (ok){ ix = deint((unsigned)node); iy = deint(((unsigned)node) >> 1); }
    unsigned msk = 0;
    #pragma unroll
    for (int m=0;m<9;++m){
      int dy = m/3 - 1, dx = m%3 - 1;
      int nx = (int)ix + dx, ny = (int)iy + dy;
      unsigned key = 0;
      if (ok && nx>=0 && ny>=0 && nx<res && ny<res){
        key = ileave((unsigned)nx) | (ileave((unsigned)ny) << 1);
        msk |= (1u << m);
      }
      kkey[t][m] = (unsigned short)key;
    }
    kmsk[t] = (unsigned short)msk;
  }
  __syncthreads();

  float4 rA[LA4];
  auto pref = [&](int m){
    #pragma unroll
    for (int j=0;j<LA4;++j){
      int e = t + j*256;
      int node = e >> 4, u = e & 15;
      bool v = (kmsk[node] >> m) & 1;
      unsigned key = kkey[node][m];
      rA[j] = v ? *((const float4*)(A + (size_t)key*64) + u)
                : make_float4(0.f,0.f,0.f,0.f);
    }
  };
  pref(0);

  int tr = t >> 3, tc = t & 7;
  float acc[R][8];
  #pragma unroll
  for (int i=0;i<R;++i)
    #pragma unroll
    for (int c=0;c<8;++c) acc[i][c] = 0.f;

  for (int m=0;m<9;++m){
    __syncthreads();                 // previous compute done reading Alt
    #pragma unroll
    for (int j=0;j<LA4;++j){
      int e = t + j*256;
      *(float4*)&Alt[e >> 4][(e & 15)*4] = rA[j];
    }
    if (m < 8) pref(m+1);            // next gather flies during compute
    __syncthreads();
    const float* Wm = W + (size_t)m*4096 + tc*8;
    #pragma unroll
    for (int k4=0;k4<16;++k4){
      float av[R][4];
      #pragma unroll
      for (int i=0;i<R;++i){
        float4 aa = *(const float4*)&Alt[tr*R+i][k4*4];
        av[i][0]=aa.x; av[i][1]=aa.y; av[i][2]=aa.z; av[i][3]=aa.w;
      }
      float w[4][8];
      const float* Wr = Wm + k4*256;
      #pragma unroll
      for (int j=0;j<4;++j){
        float4 lo = *(const float4*)(Wr + j*64);
        float4 hi = *(const float4*)(Wr + j*64 + 4);
        w[j][0]=lo.x; w[j][1]=lo.y; w[j][2]=lo.z; w[j][3]=lo.w;
        w[j][4]=hi.x; w[j][5]=hi.y; w[j][6]=hi.z; w[j][7]=hi.w;
      }
      #pragma unroll
      for (int i=0;i<R;++i)
        #pragma unroll
        for (int j=0;j<4;++j)
          #pragma unroll
          for (int c=0;c<8;++c) acc[i][c] += av[i][j]*w[j][c];
    }
  }
  float bias[8];
  #pragma unroll
  for (int c=0;c<8;++c) bias[c] = Bb[tc*8+c];
  #pragma unroll
  for (int i=0;i<R;++i){
    int node = nb + tr*R + i;
    if (node >= N) continue;
    float ov[8];
    #pragma unroll
    for (int c=0;c<8;++c){
      float v = acc[i][c] + bias[c];
      ov[c] = v > 0.f ? v : 0.f;
    }
    float* dst = &h[(size_t)(off + node)*64 + tc*8];
    *(float4*)dst       = *(const float4*)&ov[0];
    *(float4*)(dst + 4) = *(const float4*)&ov[4];
  }
}

// ---------- fused tail: d=4..1, one block; Pt[node][ch] + zero-row trick ----------
__global__ __launch_bounds__(256) void k_tail(float* __restrict__ h,
    const float* __restrict__ convW, const float* __restrict__ convB){
  __shared__ float Pt[65][68];    // row 64 = zero row for invalid neighbors
  int t = threadIdx.x;
  #pragma unroll
  for (int d = 4; d >= 1; --d){
    const int L = d - 1;
    const int Np = 1 << (2*L);   // 64,16,4,1
    for (int e = t; e < Np*16; e += 256){
      int node = e >> 4, u = e & 15;
      const float4* c = (const float4*)(h + (size_t)(OFFS[d] + 4*node)*64) + u;
      float4 c0 = c[0], c1 = c[16], c2 = c[32], c3 = c[48];
      float4 pr = *((const float4*)(h + (size_t)(OFFS[L] + node)*64) + u);
      float4 r;
      r.x = 0.25f*(c0.x+c1.x+c2.x+c3.x) + pr.x;
      r.y = 0.25f*(c0.y+c1.y+c2.y+c3.y) + pr.y;
      r.z = 0.25f*(c0.z+c1.z+c2.z+c3.z) + pr.z;
      r.w = 0.25f*(c0.w+c1.w+c2.w+c3.w) + pr.w;
      *(float4*)&Pt[node][u*4] = r;
    }
    if (t < 17) *(float4*)&Pt[64][t*4] = make_float4(0.f,0.f,0.f,0.f);
    __syncthreads();
    if (L == 0){
      if (t < 16) ((float4*)h)[t] = *(const float4*)&Pt[0][t*4];
      break;
    }
    const int R = (L == 3) ? 2 : 1;
    int tr = t >> 3, tc = t & 7;
    bool act = (tr*R) < Np;
    float acc[2][8];
    #pragma unroll
    for (int i=0;i<2;++i)
      #pragma unroll
      for (int c=0;c<8;++c) acc[i][c] = 0.f;
    unsigned ixs[2] = {0,0}, iys[2] = {0,0};
    const int res = 1 << L;
    if (act){
      #pragma unroll
      for (int i=0;i<R;++i){
        unsigned node = (unsigned)(tr*R + i);
        ixs[i] = deint(node); iys[i] = deint(node >> 1);
      }
    }
    const float* WL = convW + (size_t)L*36864;
    if (act){
      for (int m=0;m<9;++m){
        int dy = m/3 - 1, dx = m%3 - 1;
        int key[2];
        #pragma unroll
        for (int i=0;i<R;++i){
          int nx = (int)ixs[i] + dx, ny = (int)iys[i] + dy;
          key[i] = (nx>=0 && ny>=0 && nx<res && ny<res)
                 ? (int)(ileave((unsigned)nx) | (ileave((unsigned)ny) << 1)) : 64;
        }
        const float* Wm = WL + (size_t)m*4096 + tc*8;
        #pragma unroll
        for (int k4=0;k4<16;++k4){
          float av[2][4];
          #pragma unroll
          for (int i=0;i<R;++i){
            float4 aa = *(const float4*)&Pt[key[i]][k4*4];
            av[i][0]=aa.x; av[i][1]=aa.y; av[i][2]=aa.z; av[i][3]=aa.w;
          }
          float w[4][8];
          const float* Wr = Wm + k4*256;
          #pragma unroll
          for (int j=0;j<4;++j){
            float4 lo = *(const float4*)(Wr + j*64);
            float4 hi = *(const float4*)(Wr + j*64 + 4);
            w[j][0]=lo.x; w[j][1]=lo.y; w[j][2]=lo.z; w[j][3]=lo.w;
            w[j][4]=hi.x; w[j][5]=hi.y; w[j][6]=hi.z; w[j][7]=hi.w;
          }
          #pragma unroll
          for (int i=0;i<R;++i)
            #pragma unroll
            for (int j=0;j<4;++j)
              #pragma unroll
              for (int c=0;c<8;++c) acc[i][c] += av[i][j]*w[j][c];
        }
      }
      #pragma unroll
      for (int i=0;i<R;++i){
        int node = tr*R + i;
        float ov[8];
        #pragma unroll
        for (int c=0;c<8;++c){
          float v = acc[i][c] + convB[L*64 + tc*8 + c];
          ov[c] = v > 0.f ? v : 0.f;
        }
        float* dst = &h[(size_t)(OFFS[L] + node)*64 + tc*8];
        *(float4*)dst       = *(const float4*)&ov[0];
        *(float4*)(dst + 4) = *(const float4*)&ov[4];
      }
    }
    __syncthreads();   // h stores + Pt reads done before next level
  }
}

// ---------- emb + layernorm + gain, in place over h ----------
__global__ __launch_bounds__(256, 3) void k_emb(float* h, const float* __restrict__ embW,
    const float* __restrict__ embB, const float* __restrict__ lng,
    const float* __restrict__ lnb, const float* __restrict__ gain){
  int bb = blockIdx.x;
  int d = 0;
  #pragma unroll
  for (int i = 1; i <= 9; ++i) if (bb >= EBLK[i]) d = i;
  int nb = (bb - EBLK[d]) * 128;
  int N = 1 << (2*d);
  int off = OFFS[d];

  __shared__ float Alt[128][68];   // [node][k]
  int t = threadIdx.x;
  #pragma unroll
  for (int j=0;j<8;++j){
    int e = t + j*256;
    int node = e >> 4, u = e & 15;
    int g = nb + node;
    float4 v = (g < N) ? *((const float4*)(h + (size_t)(off + g)*64) + u)
                       : make_float4(0.f,0.f,0.f,0.f);
    *(float4*)&Alt[node][u*4] = v;
  }
  __syncthreads();
  const float* Wd = embW + (size_t)d*4096;
  int tr = t >> 3, tc = t & 7;
  float acc[4][8];
  #pragma unroll
  for (int c=0;c<8;++c){
    float bv = embB[d*64 + tc*8 + c];
    #pragma unroll
    for (int i=0;i<4;++i) acc[i][c] = bv;
  }
  const float* Wt = Wd + tc*8;
  #pragma unroll
  for (int k4=0;k4<16;++k4){
    float av[4][4];
    #pragma unroll
    for (int i=0;i<4;++i){
      float4 aa = *(const float4*)&Alt[tr*4+i][k4*4];
      av[i][0]=aa.x; av[i][1]=aa.y; av[i][2]=aa.z; av[i][3]=aa.w;
    }
    float w[4][8];
    const float* Wr = Wt + k4*256;
    #pragma unroll
    for (int j=0;j<4;++j){
      float4 lo = *(const float4*)(Wr + j*64);
      float4 hi = *(const float4*)(Wr + j*64 + 4);
      w[j][0]=lo.x; w[j][1]=lo.y; w[j][2]=lo.z; w[j][3]=lo.w;
      w[j][4]=hi.x; w[j][5]=hi.y; w[j][6]=hi.z; w[j][7]=hi.w;
    }
    #pragma unroll
    for (int i=0;i<4;++i)
      #pragma unroll
      for (int j=0;j<4;++j)
        #pragma unroll
        for (int c=0;c<8;++c) acc[i][c] += av[i][j]*w[j][c];
  }
  float gvals[8], bvals[8];
  #pragma unroll
  for (int c=0;c<8;++c){
    gvals[c] = lng[d*64 + tc*8 + c];
    bvals[c] = lnb[d*64 + tc*8 + c];
  }
  float gn = gain[d];
  #pragma unroll
  for (int i=0;i<4;++i){
    float s = 0.f, q = 0.f;
    #pragma unroll
    for (int c=0;c<8;++c){ s += acc[i][c]; q += acc[i][c]*acc[i][c]; }
    #pragma unroll
    for (int msk = 1; msk < 8; msk <<= 1){
      s += __shfl_xor(s, msk, 64);
      q += __shfl_xor(q, msk, 64);
    }
    float mu = s * 0.015625f;
    float var = q * 0.015625f - mu*mu;
    float rs = rsqrtf(var + 1e-5f);
    int node = nb + tr*4 + i;
    if (node < N){
      float ov[8];
      #pragma unroll
      for (int c=0;c<8;++c)
        ov[c] = ((acc[i][c] - mu) * rs * gvals[c] + bvals[c]) * gn;
      float* dst = &h[(size_t)(off + node)*64 + tc*8];
      *(float4*)dst       = *(const float4*)&ov[0];
      *(float4*)(dst + 4) = *(const float4*)&ov[4];
    }
  }
}

extern "C" void kernel_launch(void* const* d_in, const int* in_sizes, int n_in,
                              void* d_out, int out_size, void* d_ws, size_t ws_size,
                              hipStream_t stream) {
  (void)in_sizes; (void)n_in; (void)out_size; (void)ws_size;
  const float* feat  = (const float*)d_in[0];
  const float* ipW   = (const float*)d_in[1];
  const float* ipB   = (const float*)d_in[2];
  const float* convW = (const float*)d_in[3];
  const float* convB = (const float*)d_in[4];
  const float* embW  = (const float*)d_in[5];
  const float* embB  = (const float*)d_in[6];
  const float* lng   = (const float*)d_in[7];
  const float* lnb   = (const float*)d_in[8];
  const float* gain  = (const float*)d_in[9];
  float* h   = (float*)d_out;          // h lives in d_out (f32), emb runs in place
  float* stg = (float*)d_ws;           // f32 pooled staging, max 16.8 MB

  k_inproj<<<(TOTAL + 127)/128, 256, 0, stream>>>(feat, ipW, ipB, h);

  for (int d = 9; d >= 5; --d){
    int L = d - 1;
    int Np = 1 << (2*L);
    k_pool<<<(Np*16 + 255)/256, 256, 0, stream>>>(h, stg, Np, OFFS[L], OFFS[d]);
    const float* WL = convW + (size_t)L*36864;
    const float* BL = convB + (size_t)L*64;
    if (L == 8)
      k_conv<128><<<Np/128, 256, 0, stream>>>(stg, WL, BL, h, Np, OFFS[L], L);
    else if (L >= 6)
      k_conv<64><<<Np/64, 256, 0, stream>>>(stg, WL, BL, h, Np, OFFS[L], L);
    else
      k_conv<32><<<Np/32, 256, 0, stream>>>(stg, WL, BL, h, Np, OFFS[L], L);
  }

  // d=4..1 fused single-block tail
  k_tail<<<1, 256, 0, stream>>>(h, convW, convB);

  k_emb<<<2734, 256, 0, stream>>>(h, embW, embB, lng, lnb, gain);
}

// Round 5
// 1571.727 us; speedup vs baseline: 1.3556x; 1.3556x over previous
//
#include <hip/hip_runtime.h>
#include <hip/hip_bf16.h>

static constexpr int TOTAL = 349525;
static constexpr int OFFS[11] = {0,1,5,21,85,341,1365,5461,21845,87381,349525};
// emb blocks of 128 nodes per level: counts {1,1,1,1,2,8,32,128,512,2048}
static constexpr int EBLK[11] = {0,1,2,3,4,6,14,46,174,686,2734};

__device__ __forceinline__ unsigned deint(unsigned v){
  v &= 0x55555555u;
  v = (v | (v>>1)) & 0x33333333u;
  v = (v | (v>>2)) & 0x0F0F0F0Fu;
  v = (v | (v>>4)) & 0x00FF00FFu;
  v = (v | (v>>8)) & 0x0000FFFFu;
  return v;
}
__device__ __forceinline__ unsigned ileave(unsigned v){
  v &= 0xFFFFu;
  v = (v | (v<<8)) & 0x00FF00FFu;
  v = (v | (v<<4)) & 0x0F0F0F0Fu;
  v = (v | (v<<2)) & 0x33333333u;
  v = (v | (v<<1)) & 0x55555555u;
  return v;
}

// ---------- in_proj: h[g] = concat(f, posenc) @ W(40x64) + b ----------
__global__ __launch_bounds__(256) void k_inproj(const float* __restrict__ feat,
    const float* __restrict__ W, const float* __restrict__ B, float* __restrict__ h){
  __shared__ float Alt[128][44];   // [node][k], pitch 44
  int t = threadIdx.x;
  int base = blockIdx.x * 128;
  if (t < 128){
    int g = base + t;
    float* row = Alt[t];
    if (g < TOTAL){
      int d = 0;
      #pragma unroll
      for (int i = 1; i <= 9; ++i) if (g >= OFFS[i]) d = i;
      int local = g - OFFS[d];
      unsigned ix = deint((unsigned)local), iy = deint(((unsigned)local) >> 1);
      float inv = 1.0f / (float)(1 << d);
      float px = ((float)ix + 0.5f) * inv;
      float py = ((float)iy + 0.5f) * inv;
      float pd = (float)d * (1.0f/9.0f);
      row[0] = feat[g]; row[1] = px; row[2] = py; row[3] = pd;
      float p3[3] = {px, py, pd};
      #pragma unroll
      for (int c = 0; c < 3; ++c){
        float s, co;
        __sincosf(6.28318530717958647692f * p3[c], &s, &co);
        float* rb = row + 4 + c*12;
        #pragma unroll
        for (int f = 0; f < 6; ++f){
          rb[f] = s; rb[6+f] = co;
          float s2 = 2.f*s*co, c2 = 1.f - 2.f*s*s;
          s = s2; co = c2;
        }
      }
    } else {
      #pragma unroll
      for (int k = 0; k < 40; ++k) row[k] = 0.f;
    }
  }
  __syncthreads();
  int tr = t >> 3, tc = t & 7;        // 4 nodes x 8 ch
  float acc[4][8];
  #pragma unroll
  for (int i=0;i<4;++i)
    #pragma unroll
    for (int c=0;c<8;++c) acc[i][c] = 0.f;
  const float* Wt = W + tc*8;
  #pragma unroll
  for (int k4 = 0; k4 < 10; ++k4){
    float av4[4][4];
    #pragma unroll
    for (int i=0;i<4;++i){
      float4 aa = *(const float4*)&Alt[tr*4+i][k4*4];
      av4[i][0]=aa.x; av4[i][1]=aa.y; av4[i][2]=aa.z; av4[i][3]=aa.w;
    }
    const float* Wr = Wt + k4*256;
    #pragma unroll
    for (int j=0;j<4;++j){
      float4 lo = *(const float4*)(Wr + j*64);
      float4 hi = *(const float4*)(Wr + j*64 + 4);
      float wv[8];
      wv[0]=lo.x; wv[1]=lo.y; wv[2]=lo.z; wv[3]=lo.w;
      wv[4]=hi.x; wv[5]=hi.y; wv[6]=hi.z; wv[7]=hi.w;
      #pragma unroll
      for (int i=0;i<4;++i){
        float a = av4[i][j];
        #pragma unroll
        for (int c=0;c<8;++c) acc[i][c] += a*wv[c];
      }
    }
  }
  #pragma unroll
  for (int i=0;i<4;++i){
    int g = base + tr*4 + i;
    if (g >= TOTAL) continue;
    float ov[8];
    #pragma unroll
    for (int c=0;c<8;++c) ov[c] = acc[i][c] + B[tc*8+c];
    float* dst = &h[(size_t)g*64 + tc*8];
    *(float4*)dst       = *(const float4*)&ov[0];
    *(float4*)(dst + 4) = *(const float4*)&ov[4];
  }
}

// ---------- pool: stg[p] = h[parent p] + mean(children), float4 ----------
__global__ __launch_bounds__(256) void k_pool(const float* __restrict__ h,
    float* __restrict__ stg, int Np, int offPar, int offChild){
  int e = blockIdx.x*256 + threadIdx.x;
  if (e >= Np*16) return;
  int p = e >> 4, u = e & 15;
  const float4* c = (const float4*)(h + (size_t)(offChild + 4*p)*64) + u;
  float4 c0 = c[0], c1 = c[16], c2 = c[32], c3 = c[48];
  float4 pr = *((const float4*)(h + (size_t)(offPar + p)*64) + u);
  float4 r;
  r.x = 0.25f*(c0.x+c1.x+c2.x+c3.x) + pr.x;
  r.y = 0.25f*(c0.y+c1.y+c2.y+c3.y) + pr.y;
  r.z = 0.25f*(c0.z+c1.z+c2.z+c3.z) + pr.z;
  r.w = 0.25f*(c0.w+c1.w+c2.w+c3.w) + pr.w;
  ((float4*)stg)[e] = r;
}

// ---------- conv: h[L] = relu( gather9(stg) @ conv_W[L] + b ), 64 nodes/block ----------
__global__ __launch_bounds__(256) void k_conv(const float* __restrict__ A,
    const float* __restrict__ W, const float* __restrict__ Bb, float* __restrict__ h,
    int N, int off, int lbits){
  constexpr int NPB = 64, R = 2, LA4 = 4;
  __shared__ float Alt[NPB][68];    // [node][kk]
  __shared__ unsigned short kkey[NPB][9];
  __shared__ unsigned short kmsk[NPB];
  int t = threadIdx.x;
  int nb = blockIdx.x * NPB;
  if (t < NPB){
    int node = nb + t;
    int res = 1 << lbits;
    bool ok = node < N;
    unsigned ix = 0, iy = 0;
    if (ok){ ix = deint((unsigned)node); iy = deint(((unsigned)node) >> 1); }
    unsigned msk = 0;
    #pragma unroll
    for (int m=0;m<9;++m){
      int dy = m/3 - 1, dx = m%3 - 1;
      int nx = (int)ix + dx, ny = (int)iy + dy;
      unsigned key = 0;
      if (ok && nx>=0 && ny>=0 && nx<res && ny<res){
        key = ileave((unsigned)nx) | (ileave((unsigned)ny) << 1);
        msk |= (1u << m);
      }
      kkey[t][m] = (unsigned short)key;
    }
    kmsk[t] = (unsigned short)msk;
  }
  __syncthreads();

  float4 rA[LA4];
  auto pref = [&](int m){
    #pragma unroll
    for (int j=0;j<LA4;++j){
      int e = t + j*256;
      int node = e >> 4, u = e & 15;
      bool v = (kmsk[node] >> m) & 1;
      unsigned key = kkey[node][m];
      rA[j] = v ? *((const float4*)(A + (size_t)key*64) + u)
                : make_float4(0.f,0.f,0.f,0.f);
    }
  };
  pref(0);

  int tr = t >> 3, tc = t & 7;
  float acc[R][8];
  #pragma unroll
  for (int i=0;i<R;++i)
    #pragma unroll
    for (int c=0;c<8;++c) acc[i][c] = 0.f;

  for (int m=0;m<9;++m){
    __syncthreads();                 // previous compute done reading Alt
    #pragma unroll
    for (int j=0;j<LA4;++j){
      int e = t + j*256;
      *(float4*)&Alt[e >> 4][(e & 15)*4] = rA[j];
    }
    if (m < 8) pref(m+1);            // next gather flies during compute (T14)
    __syncthreads();
    const float* Wm = W + (size_t)m*4096 + tc*8;
    #pragma unroll
    for (int k4=0;k4<16;++k4){
      float av4[R][4];
      #pragma unroll
      for (int i=0;i<R;++i){
        float4 aa = *(const float4*)&Alt[tr*R+i][k4*4];
        av4[i][0]=aa.x; av4[i][1]=aa.y; av4[i][2]=aa.z; av4[i][3]=aa.w;
      }
      const float* Wr = Wm + k4*256;
      #pragma unroll
      for (int j=0;j<4;++j){
        float4 lo = *(const float4*)(Wr + j*64);
        float4 hi = *(const float4*)(Wr + j*64 + 4);
        float wv[8];
        wv[0]=lo.x; wv[1]=lo.y; wv[2]=lo.z; wv[3]=lo.w;
        wv[4]=hi.x; wv[5]=hi.y; wv[6]=hi.z; wv[7]=hi.w;
        #pragma unroll
        for (int i=0;i<R;++i){
          float a = av4[i][j];
          #pragma unroll
          for (int c=0;c<8;++c) acc[i][c] += a*wv[c];
        }
      }
    }
  }
  #pragma unroll
  for (int i=0;i<R;++i){
    int node = nb + tr*R + i;
    if (node >= N) continue;
    float ov[8];
    #pragma unroll
    for (int c=0;c<8;++c){
      float v = acc[i][c] + Bb[tc*8+c];
      ov[c] = v > 0.f ? v : 0.f;
    }
    float* dst = &h[(size_t)(off + node)*64 + tc*8];
    *(float4*)dst       = *(const float4*)&ov[0];
    *(float4*)(dst + 4) = *(const float4*)&ov[4];
  }
}

// ---------- fused tail: d=4..1, one block; Pt[node][ch] + zero-row trick ----------
__global__ __launch_bounds__(256) void k_tail(float* __restrict__ h,
    const float* __restrict__ convW, const float* __restrict__ convB){
  __shared__ float Pt[65][68];    // row 64 = zero row for invalid neighbors
  int t = threadIdx.x;
  #pragma unroll
  for (int d = 4; d >= 1; --d){
    const int L = d - 1;
    const int Np = 1 << (2*L);   // 64,16,4,1
    for (int e = t; e < Np*16; e += 256){
      int node = e >> 4, u = e & 15;
      const float4* c = (const float4*)(h + (size_t)(OFFS[d] + 4*node)*64) + u;
      float4 c0 = c[0], c1 = c[16], c2 = c[32], c3 = c[48];
      float4 pr = *((const float4*)(h + (size_t)(OFFS[L] + node)*64) + u);
      float4 r;
      r.x = 0.25f*(c0.x+c1.x+c2.x+c3.x) + pr.x;
      r.y = 0.25f*(c0.y+c1.y+c2.y+c3.y) + pr.y;
      r.z = 0.25f*(c0.z+c1.z+c2.z+c3.z) + pr.z;
      r.w = 0.25f*(c0.w+c1.w+c2.w+c3.w) + pr.w;
      *(float4*)&Pt[node][u*4] = r;
    }
    if (t < 17) *(float4*)&Pt[64][t*4] = make_float4(0.f,0.f,0.f,0.f);
    __syncthreads();
    if (L == 0){
      if (t < 16) ((float4*)h)[t] = *(const float4*)&Pt[0][t*4];
      break;
    }
    const int R = (L == 3) ? 2 : 1;
    int tr = t >> 3, tc = t & 7;
    bool act = (tr*R) < Np;
    float acc[2][8];
    #pragma unroll
    for (int i=0;i<2;++i)
      #pragma unroll
      for (int c=0;c<8;++c) acc[i][c] = 0.f;
    unsigned ixs[2] = {0,0}, iys[2] = {0,0};
    const int res = 1 << L;
    if (act){
      #pragma unroll
      for (int i=0;i<R;++i){
        unsigned node = (unsigned)(tr*R + i);
        ixs[i] = deint(node); iys[i] = deint(node >> 1);
      }
    }
    const float* WL = convW + (size_t)L*36864;
    if (act){
      for (int m=0;m<9;++m){
        int dy = m/3 - 1, dx = m%3 - 1;
        int key[2];
        #pragma unroll
        for (int i=0;i<R;++i){
          int nx = (int)ixs[i] + dx, ny = (int)iys[i] + dy;
          key[i] = (nx>=0 && ny>=0 && nx<res && ny<res)
                 ? (int)(ileave((unsigned)nx) | (ileave((unsigned)ny) << 1)) : 64;
        }
        const float* Wm = WL + (size_t)m*4096 + tc*8;
        #pragma unroll
        for (int k4=0;k4<16;++k4){
          float av4[2][4];
          #pragma unroll
          for (int i=0;i<R;++i){
            float4 aa = *(const float4*)&Pt[key[i]][k4*4];
            av4[i][0]=aa.x; av4[i][1]=aa.y; av4[i][2]=aa.z; av4[i][3]=aa.w;
          }
          const float* Wr = Wm + k4*256;
          #pragma unroll
          for (int j=0;j<4;++j){
            float4 lo = *(const float4*)(Wr + j*64);
            float4 hi = *(const float4*)(Wr + j*64 + 4);
            float wv[8];
            wv[0]=lo.x; wv[1]=lo.y; wv[2]=lo.z; wv[3]=lo.w;
            wv[4]=hi.x; wv[5]=hi.y; wv[6]=hi.z; wv[7]=hi.w;
            #pragma unroll
            for (int i=0;i<R;++i){
              float a = av4[i][j];
              #pragma unroll
              for (int c=0;c<8;++c) acc[i][c] += a*wv[c];
            }
          }
        }
      }
      #pragma unroll
      for (int i=0;i<R;++i){
        int node = tr*R + i;
        float ov[8];
        #pragma unroll
        for (int c=0;c<8;++c){
          float v = acc[i][c] + convB[L*64 + tc*8 + c];
          ov[c] = v > 0.f ? v : 0.f;
        }
        float* dst = &h[(size_t)(OFFS[L] + node)*64 + tc*8];
        *(float4*)dst       = *(const float4*)&ov[0];
        *(float4*)(dst + 4) = *(const float4*)&ov[4];
      }
    }
    __syncthreads();   // h stores + Pt reads done before next level
  }
}

// ---------- emb + layernorm + gain, in place over h ----------
__global__ __launch_bounds__(256) void k_emb(float* h, const float* __restrict__ embW,
    const float* __restrict__ embB, const float* __restrict__ lng,
    const float* __restrict__ lnb, const float* __restrict__ gain){
  int bb = blockIdx.x;
  int d = 0;
  #pragma unroll
  for (int i = 1; i <= 9; ++i) if (bb >= EBLK[i]) d = i;
  int nb = (bb - EBLK[d]) * 128;
  int N = 1 << (2*d);
  int off = OFFS[d];

  __shared__ float Alt[128][68];   // [node][k]
  int t = threadIdx.x;
  #pragma unroll
  for (int j=0;j<8;++j){
    int e = t + j*256;
    int node = e >> 4, u = e & 15;
    int g = nb + node;
    float4 v = (g < N) ? *((const float4*)(h + (size_t)(off + g)*64) + u)
                       : make_float4(0.f,0.f,0.f,0.f);
    *(float4*)&Alt[node][u*4] = v;
  }
  __syncthreads();
  const float* Wd = embW + (size_t)d*4096;
  int tr = t >> 3, tc = t & 7;
  float acc[4][8];
  #pragma unroll
  for (int c=0;c<8;++c){
    float bv = embB[d*64 + tc*8 + c];
    #pragma unroll
    for (int i=0;i<4;++i) acc[i][c] = bv;
  }
  const float* Wt = Wd + tc*8;
  #pragma unroll
  for (int k4=0;k4<16;++k4){
    float av4[4][4];
    #pragma unroll
    for (int i=0;i<4;++i){
      float4 aa = *(const float4*)&Alt[tr*4+i][k4*4];
      av4[i][0]=aa.x; av4[i][1]=aa.y; av4[i][2]=aa.z; av4[i][3]=aa.w;
    }
    const float* Wr = Wt + k4*256;
    #pragma unroll
    for (int j=0;j<4;++j){
      float4 lo = *(const float4*)(Wr + j*64);
      float4 hi = *(const float4*)(Wr + j*64 + 4);
      float wv[8];
      wv[0]=lo.x; wv[1]=lo.y; wv[2]=lo.z; wv[3]=lo.w;
      wv[4]=hi.x; wv[5]=hi.y; wv[6]=hi.z; wv[7]=hi.w;
      #pragma unroll
      for (int i=0;i<4;++i){
        float a = av4[i][j];
        #pragma unroll
        for (int c=0;c<8;++c) acc[i][c] += a*wv[c];
      }
    }
  }
  float gvals[8], bvals[8];
  #pragma unroll
  for (int c=0;c<8;++c){
    gvals[c] = lng[d*64 + tc*8 + c];
    bvals[c] = lnb[d*64 + tc*8 + c];
  }
  float gn = gain[d];
  #pragma unroll
  for (int i=0;i<4;++i){
    float s = 0.f, q = 0.f;
    #pragma unroll
    for (int c=0;c<8;++c){ s += acc[i][c]; q += acc[i][c]*acc[i][c]; }
    #pragma unroll
    for (int msk = 1; msk < 8; msk <<= 1){
      s += __shfl_xor(s, msk, 64);
      q += __shfl_xor(q, msk, 64);
    }
    float mu = s * 0.015625f;
    float var = q * 0.015625f - mu*mu;
    float rs = rsqrtf(var + 1e-5f);
    int node = nb + tr*4 + i;
    if (node < N){
      float ov[8];
      #pragma unroll
      for (int c=0;c<8;++c)
        ov[c] = ((acc[i][c] - mu) * rs * gvals[c] + bvals[c]) * gn;
      float* dst = &h[(size_t)(off + node)*64 + tc*8];
      *(float4*)dst       = *(const float4*)&ov[0];
      *(float4*)(dst + 4) = *(const float4*)&ov[4];
    }
  }
}

extern "C" void kernel_launch(void* const* d_in, const int* in_sizes, int n_in,
                              void* d_out, int out_size, void* d_ws, size_t ws_size,
                              hipStream_t stream) {
  (void)in_sizes; (void)n_in; (void)out_size; (void)ws_size;
  const float* feat  = (const float*)d_in[0];
  const float* ipW   = (const float*)d_in[1];
  const float* ipB   = (const float*)d_in[2];
  const float* convW = (const float*)d_in[3];
  const float* convB = (const float*)d_in[4];
  const float* embW  = (const float*)d_in[5];
  const float* embB  = (const float*)d_in[6];
  const float* lng   = (const float*)d_in[7];
  const float* lnb   = (const float*)d_in[8];
  const float* gain  = (const float*)d_in[9];
  float* h   = (float*)d_out;          // h lives in d_out (f32), emb runs in place
  float* stg = (float*)d_ws;           // f32 pooled staging, max 16.8 MB

  k_inproj<<<(TOTAL + 127)/128, 256, 0, stream>>>(feat, ipW, ipB, h);

  for (int d = 9; d >= 5; --d){
    int L = d - 1;
    int Np = 1 << (2*L);
    k_pool<<<(Np*16 + 255)/256, 256, 0, stream>>>(h, stg, Np, OFFS[L], OFFS[d]);
    k_conv<<<Np/64, 256, 0, stream>>>(stg, convW + (size_t)L*36864,
        convB + (size_t)L*64, h, Np, OFFS[L], L);
  }

  // d=4..1 fused single-block tail
  k_tail<<<1, 256, 0, stream>>>(h, convW, convB);

  k_emb<<<2734, 256, 0, stream>>>(h, embW, embB, lng, lnb, gain);
}

// Round 6
// 431.803 us; speedup vs baseline: 4.9342x; 3.6399x over previous
//
#include <hip/hip_runtime.h>
#include <hip/hip_bf16.h>

static constexpr int TOTAL = 349525;
static constexpr int OFFS[11] = {0,1,5,21,85,341,1365,5461,21845,87381,349525};
// emb blocks of 128 nodes per level: counts {1,1,1,1,2,8,32,128,512,2048}
static constexpr int EBLK[11] = {0,1,2,3,4,6,14,46,174,686,2734};

__device__ __forceinline__ unsigned deint(unsigned v){
  v &= 0x55555555u;
  v = (v | (v>>1)) & 0x33333333u;
  v = (v | (v>>2)) & 0x0F0F0F0Fu;
  v = (v | (v>>4)) & 0x00FF00FFu;
  v = (v | (v>>8)) & 0x0000FFFFu;
  return v;
}
__device__ __forceinline__ unsigned ileave(unsigned v){
  v &= 0xFFFFu;
  v = (v | (v<<8)) & 0x00FF00FFu;
  v = (v | (v<<4)) & 0x0F0F0F0Fu;
  v = (v | (v<<2)) & 0x33333333u;
  v = (v | (v<<1)) & 0x55555555u;
  return v;
}

// ---------- in_proj: h[g] = concat(f, posenc) @ W(40x64) + b ----------
__global__ __launch_bounds__(256) void k_inproj(const float* __restrict__ feat,
    const float* __restrict__ W, const float* __restrict__ B, float* __restrict__ h){
  __shared__ float Alt[128][44];   // [node][k], pitch 44
  __shared__ float Wl[40][68];     // [k][ch], rows 16B-aligned
  int t = threadIdx.x;
  int base = blockIdx.x * 128;
  for (int idx = t; idx < 40*64; idx += 256)
    Wl[idx >> 6][idx & 63] = W[idx];
  if (t < 128){
    int g = base + t;
    float* row = Alt[t];
    if (g < TOTAL){
      int d = 0;
      #pragma unroll
      for (int i = 1; i <= 9; ++i) if (g >= OFFS[i]) d = i;
      int local = g - OFFS[d];
      unsigned ix = deint((unsigned)local), iy = deint(((unsigned)local) >> 1);
      float inv = 1.0f / (float)(1 << d);
      float px = ((float)ix + 0.5f) * inv;
      float py = ((float)iy + 0.5f) * inv;
      float pd = (float)d * (1.0f/9.0f);
      row[0] = feat[g]; row[1] = px; row[2] = py; row[3] = pd;
      float p3[3] = {px, py, pd};
      #pragma unroll
      for (int c = 0; c < 3; ++c){
        float s, co;
        __sincosf(6.28318530717958647692f * p3[c], &s, &co);
        float* rb = row + 4 + c*12;
        #pragma unroll
        for (int f = 0; f < 6; ++f){
          rb[f] = s; rb[6+f] = co;
          float s2 = 2.f*s*co, c2 = 1.f - 2.f*s*s;
          s = s2; co = c2;
        }
      }
    } else {
      #pragma unroll
      for (int k = 0; k < 40; ++k) row[k] = 0.f;
    }
  }
  __syncthreads();
  int tr = t >> 3, tc = t & 7;        // 4 nodes x 8 ch
  float acc[4][8];
  #pragma unroll
  for (int i=0;i<4;++i)
    #pragma unroll
    for (int c=0;c<8;++c) acc[i][c] = 0.f;
  #pragma unroll 2
  for (int k4 = 0; k4 < 10; ++k4){
    float av4[4][4];
    #pragma unroll
    for (int i=0;i<4;++i){
      float4 aa = *(const float4*)&Alt[tr*4+i][k4*4];
      av4[i][0]=aa.x; av4[i][1]=aa.y; av4[i][2]=aa.z; av4[i][3]=aa.w;
    }
    #pragma unroll
    for (int j=0;j<4;++j){
      float4 lo = *(const float4*)&Wl[k4*4+j][tc*8];
      float4 hi = *(const float4*)&Wl[k4*4+j][tc*8+4];
      float wv[8];
      wv[0]=lo.x; wv[1]=lo.y; wv[2]=lo.z; wv[3]=lo.w;
      wv[4]=hi.x; wv[5]=hi.y; wv[6]=hi.z; wv[7]=hi.w;
      #pragma unroll
      for (int i=0;i<4;++i){
        float a = av4[i][j];
        #pragma unroll
        for (int c=0;c<8;++c) acc[i][c] += a*wv[c];
      }
    }
  }
  #pragma unroll
  for (int i=0;i<4;++i){
    int g = base + tr*4 + i;
    if (g >= TOTAL) continue;
    float ov[8];
    #pragma unroll
    for (int c=0;c<8;++c) ov[c] = acc[i][c] + B[tc*8+c];
    float* dst = &h[(size_t)g*64 + tc*8];
    *(float4*)dst       = *(const float4*)&ov[0];
    *(float4*)(dst + 4) = *(const float4*)&ov[4];
  }
}

// ---------- pool: stg[p] = h[parent p] + mean(children), float4 ----------
__global__ __launch_bounds__(256) void k_pool(const float* __restrict__ h,
    float* __restrict__ stg, int Np, int offPar, int offChild){
  int e = blockIdx.x*256 + threadIdx.x;
  if (e >= Np*16) return;
  int p = e >> 4, u = e & 15;
  const float4* c = (const float4*)(h + (size_t)(offChild + 4*p)*64) + u;
  float4 c0 = c[0], c1 = c[16], c2 = c[32], c3 = c[48];
  float4 pr = *((const float4*)(h + (size_t)(offPar + p)*64) + u);
  float4 r;
  r.x = 0.25f*(c0.x+c1.x+c2.x+c3.x) + pr.x;
  r.y = 0.25f*(c0.y+c1.y+c2.y+c3.y) + pr.y;
  r.z = 0.25f*(c0.z+c1.z+c2.z+c3.z) + pr.z;
  r.w = 0.25f*(c0.w+c1.w+c2.w+c3.w) + pr.w;
  ((float4*)stg)[e] = r;
}

// ---------- conv: h[L] = relu( gather9(stg) @ conv_W[L] + b ), 64 nodes/block ----------
// T14: prefetch next m's gather AND W slice into registers during compute.
__global__ __launch_bounds__(256) void k_conv(const float* __restrict__ A,
    const float* __restrict__ W, const float* __restrict__ Bb, float* __restrict__ h,
    int N, int off, int lbits){
  constexpr int NPB = 64, R = 2, LA4 = 4;
  __shared__ float Alt[NPB][68];    // [node][kk]
  __shared__ float Wl[64][68];      // [kk][ch]
  __shared__ unsigned short kkey[NPB][9];
  __shared__ unsigned short kmsk[NPB];
  int t = threadIdx.x;
  int nb = blockIdx.x * NPB;
  if (t < NPB){
    int node = nb + t;
    int res = 1 << lbits;
    bool ok = node < N;
    unsigned ix = 0, iy = 0;
    if (ok){ ix = deint((unsigned)node); iy = deint(((unsigned)node) >> 1); }
    unsigned msk = 0;
    #pragma unroll
    for (int m=0;m<9;++m){
      int dy = m/3 - 1, dx = m%3 - 1;
      int nx = (int)ix + dx, ny = (int)iy + dy;
      unsigned key = 0;
      if (ok && nx>=0 && ny>=0 && nx<res && ny<res){
        key = ileave((unsigned)nx) | (ileave((unsigned)ny) << 1);
        msk |= (1u << m);
      }
      kkey[t][m] = (unsigned short)key;
    }
    kmsk[t] = (unsigned short)msk;
  }
  __syncthreads();

  float4 rA[LA4];
  float4 rW[4];
  auto pref = [&](int m){
    #pragma unroll
    for (int j=0;j<LA4;++j){
      int e = t + j*256;
      int node = e >> 4, u = e & 15;
      bool v = (kmsk[node] >> m) & 1;
      unsigned key = kkey[node][m];
      rA[j] = v ? *((const float4*)(A + (size_t)key*64) + u)
                : make_float4(0.f,0.f,0.f,0.f);
    }
    const float4* W4 = (const float4*)(W + (size_t)m*4096);
    #pragma unroll
    for (int j=0;j<4;++j) rW[j] = W4[t*4 + j];
  };
  pref(0);

  int tr = t >> 3, tc = t & 7;
  float acc[R][8];
  #pragma unroll
  for (int i=0;i<R;++i)
    #pragma unroll
    for (int c=0;c<8;++c) acc[i][c] = 0.f;

  for (int m=0;m<9;++m){
    __syncthreads();                 // previous compute done reading Alt/Wl
    #pragma unroll
    for (int j=0;j<LA4;++j){
      int e = t + j*256;
      *(float4*)&Alt[e >> 4][(e & 15)*4] = rA[j];
    }
    {
      int kk = t >> 2, c0 = (t & 3)*16;
      #pragma unroll
      for (int j=0;j<4;++j) *(float4*)&Wl[kk][c0 + 4*j] = rW[j];
    }
    if (m < 8) pref(m+1);            // next gather+W fly during compute (T14)
    __syncthreads();
    #pragma unroll 2
    for (int k4=0;k4<16;++k4){
      float av4[R][4];
      #pragma unroll
      for (int i=0;i<R;++i){
        float4 aa = *(const float4*)&Alt[tr*R+i][k4*4];
        av4[i][0]=aa.x; av4[i][1]=aa.y; av4[i][2]=aa.z; av4[i][3]=aa.w;
      }
      #pragma unroll
      for (int j=0;j<4;++j){
        float4 lo = *(const float4*)&Wl[k4*4+j][tc*8];
        float4 hi = *(const float4*)&Wl[k4*4+j][tc*8+4];
        float wv[8];
        wv[0]=lo.x; wv[1]=lo.y; wv[2]=lo.z; wv[3]=lo.w;
        wv[4]=hi.x; wv[5]=hi.y; wv[6]=hi.z; wv[7]=hi.w;
        #pragma unroll
        for (int i=0;i<R;++i){
          float a = av4[i][j];
          #pragma unroll
          for (int c=0;c<8;++c) acc[i][c] += a*wv[c];
        }
      }
    }
  }
  #pragma unroll
  for (int i=0;i<R;++i){
    int node = nb + tr*R + i;
    if (node >= N) continue;
    float ov[8];
    #pragma unroll
    for (int c=0;c<8;++c){
      float v = acc[i][c] + Bb[tc*8+c];
      ov[c] = v > 0.f ? v : 0.f;
    }
    float* dst = &h[(size_t)(off + node)*64 + tc*8];
    *(float4*)dst       = *(const float4*)&ov[0];
    *(float4*)(dst + 4) = *(const float4*)&ov[4];
  }
}

// ---------- fused tail: d=4..1, one block; Pt + zero-row; Wl staged per m ----------
__global__ __launch_bounds__(256) void k_tail(float* __restrict__ h,
    const float* __restrict__ convW, const float* __restrict__ convB){
  __shared__ float Pt[65][68];    // row 64 = zero row for invalid neighbors
  __shared__ float Wl[64][68];
  int t = threadIdx.x;
  #pragma unroll
  for (int d = 4; d >= 1; --d){
    const int L = d - 1;
    const int Np = 1 << (2*L);   // 64,16,4,1
    for (int e = t; e < Np*16; e += 256){
      int node = e >> 4, u = e & 15;
      const float4* c = (const float4*)(h + (size_t)(OFFS[d] + 4*node)*64) + u;
      float4 c0 = c[0], c1 = c[16], c2 = c[32], c3 = c[48];
      float4 pr = *((const float4*)(h + (size_t)(OFFS[L] + node)*64) + u);
      float4 r;
      r.x = 0.25f*(c0.x+c1.x+c2.x+c3.x) + pr.x;
      r.y = 0.25f*(c0.y+c1.y+c2.y+c3.y) + pr.y;
      r.z = 0.25f*(c0.z+c1.z+c2.z+c3.z) + pr.z;
      r.w = 0.25f*(c0.w+c1.w+c2.w+c3.w) + pr.w;
      *(float4*)&Pt[node][u*4] = r;
    }
    if (t < 17) *(float4*)&Pt[64][t*4] = make_float4(0.f,0.f,0.f,0.f);
    __syncthreads();
    if (L == 0){
      if (t < 16) ((float4*)h)[t] = *(const float4*)&Pt[0][t*4];
      break;
    }
    const int R = (L == 3) ? 2 : 1;
    const int res = 1 << L;
    int tr = t >> 3, tc = t & 7;
    bool act = (tr*R) < Np;
    float acc[2][8];
    #pragma unroll
    for (int i=0;i<2;++i)
      #pragma unroll
      for (int c=0;c<8;++c) acc[i][c] = 0.f;
    unsigned ixs[2] = {0,0}, iys[2] = {0,0};
    if (act){
      #pragma unroll
      for (int i=0;i<R;++i){
        unsigned node = (unsigned)(tr*R + i);
        ixs[i] = deint(node); iys[i] = deint(node >> 1);
      }
    }
    const float* WL = convW + (size_t)L*36864;
    float4 rW[4];
    {
      const float4* W4 = (const float4*)WL;
      #pragma unroll
      for (int j=0;j<4;++j) rW[j] = W4[t*4 + j];
    }
    for (int m=0;m<9;++m){
      __syncthreads();               // prev compute done reading Wl
      {
        int kk = t >> 2, c0 = (t & 3)*16;
        #pragma unroll
        for (int j=0;j<4;++j) *(float4*)&Wl[kk][c0 + 4*j] = rW[j];
      }
      if (m < 8){
        const float4* W4 = (const float4*)(WL + (size_t)(m+1)*4096);
        #pragma unroll
        for (int j=0;j<4;++j) rW[j] = W4[t*4 + j];
      }
      __syncthreads();
      if (act){
        int dy = m/3 - 1, dx = m%3 - 1;
        int key[2];
        #pragma unroll
        for (int i=0;i<R;++i){
          int nx = (int)ixs[i] + dx, ny = (int)iys[i] + dy;
          key[i] = (nx>=0 && ny>=0 && nx<res && ny<res)
                 ? (int)(ileave((unsigned)nx) | (ileave((unsigned)ny) << 1)) : 64;
        }
        #pragma unroll 2
        for (int k4=0;k4<16;++k4){
          float av4[2][4];
          #pragma unroll
          for (int i=0;i<R;++i){
            float4 aa = *(const float4*)&Pt[key[i]][k4*4];
            av4[i][0]=aa.x; av4[i][1]=aa.y; av4[i][2]=aa.z; av4[i][3]=aa.w;
          }
          #pragma unroll
          for (int j=0;j<4;++j){
            float4 lo = *(const float4*)&Wl[k4*4+j][tc*8];
            float4 hi = *(const float4*)&Wl[k4*4+j][tc*8+4];
            float wv[8];
            wv[0]=lo.x; wv[1]=lo.y; wv[2]=lo.z; wv[3]=lo.w;
            wv[4]=hi.x; wv[5]=hi.y; wv[6]=hi.z; wv[7]=hi.w;
            #pragma unroll
            for (int i=0;i<R;++i){
              float a = av4[i][j];
              #pragma unroll
              for (int c=0;c<8;++c) acc[i][c] += a*wv[c];
            }
          }
        }
      }
    }
    __syncthreads();   // all Pt/Wl reads done before h stores / next level
    if (act){
      #pragma unroll
      for (int i=0;i<R;++i){
        int node = tr*R + i;
        float ov[8];
        #pragma unroll
        for (int c=0;c<8;++c){
          float v = acc[i][c] + convB[L*64 + tc*8 + c];
          ov[c] = v > 0.f ? v : 0.f;
        }
        float* dst = &h[(size_t)(OFFS[L] + node)*64 + tc*8];
        *(float4*)dst       = *(const float4*)&ov[0];
        *(float4*)(dst + 4) = *(const float4*)&ov[4];
      }
    }
    __syncthreads();
  }
}

// ---------- emb + layernorm + gain, in place over h ----------
__global__ __launch_bounds__(256) void k_emb(float* h, const float* __restrict__ embW,
    const float* __restrict__ embB, const float* __restrict__ lng,
    const float* __restrict__ lnb, const float* __restrict__ gain){
  int bb = blockIdx.x;
  int d = 0;
  #pragma unroll
  for (int i = 1; i <= 9; ++i) if (bb >= EBLK[i]) d = i;
  int nb = (bb - EBLK[d]) * 128;
  int N = 1 << (2*d);
  int off = OFFS[d];

  __shared__ float Alt[128][68];   // [node][k]
  __shared__ float Wl[64][68];     // [k][ch]
  int t = threadIdx.x;
  #pragma unroll
  for (int j=0;j<8;++j){
    int e = t + j*256;
    int node = e >> 4, u = e & 15;
    int g = nb + node;
    float4 v = (g < N) ? *((const float4*)(h + (size_t)(off + g)*64) + u)
                       : make_float4(0.f,0.f,0.f,0.f);
    *(float4*)&Alt[node][u*4] = v;
  }
  const float* Wd = embW + (size_t)d*4096;
  for (int idx = t; idx < 4096; idx += 256)
    Wl[idx >> 6][idx & 63] = Wd[idx];
  __syncthreads();
  int tr = t >> 3, tc = t & 7;
  float acc[4][8];
  #pragma unroll
  for (int c=0;c<8;++c){
    float bv = embB[d*64 + tc*8 + c];
    #pragma unroll
    for (int i=0;i<4;++i) acc[i][c] = bv;
  }
  #pragma unroll 2
  for (int k4=0;k4<16;++k4){
    float av4[4][4];
    #pragma unroll
    for (int i=0;i<4;++i){
      float4 aa = *(const float4*)&Alt[tr*4+i][k4*4];
      av4[i][0]=aa.x; av4[i][1]=aa.y; av4[i][2]=aa.z; av4[i][3]=aa.w;
    }
    #pragma unroll
    for (int j=0;j<4;++j){
      float4 lo = *(const float4*)&Wl[k4*4+j][tc*8];
      float4 hi = *(const float4*)&Wl[k4*4+j][tc*8+4];
      float wv[8];
      wv[0]=lo.x; wv[1]=lo.y; wv[2]=lo.z; wv[3]=lo.w;
      wv[4]=hi.x; wv[5]=hi.y; wv[6]=hi.z; wv[7]=hi.w;
      #pragma unroll
      for (int i=0;i<4;++i){
        float a = av4[i][j];
        #pragma unroll
        for (int c=0;c<8;++c) acc[i][c] += a*wv[c];
      }
    }
  }
  float gvals[8], bvals[8];
  #pragma unroll
  for (int c=0;c<8;++c){
    gvals[c] = lng[d*64 + tc*8 + c];
    bvals[c] = lnb[d*64 + tc*8 + c];
  }
  float gn = gain[d];
  #pragma unroll
  for (int i=0;i<4;++i){
    float s = 0.f, q = 0.f;
    #pragma unroll
    for (int c=0;c<8;++c){ s += acc[i][c]; q += acc[i][c]*acc[i][c]; }
    #pragma unroll
    for (int msk = 1; msk < 8; msk <<= 1){
      s += __shfl_xor(s, msk, 64);
      q += __shfl_xor(q, msk, 64);
    }
    float mu = s * 0.015625f;
    float var = q * 0.015625f - mu*mu;
    float rs = rsqrtf(var + 1e-5f);
    int node = nb + tr*4 + i;
    if (node < N){
      float ov[8];
      #pragma unroll
      for (int c=0;c<8;++c)
        ov[c] = ((acc[i][c] - mu) * rs * gvals[c] + bvals[c]) * gn;
      float* dst = &h[(size_t)(off + node)*64 + tc*8];
      *(float4*)dst       = *(const float4*)&ov[0];
      *(float4*)(dst + 4) = *(const float4*)&ov[4];
    }
  }
}

extern "C" void kernel_launch(void* const* d_in, const int* in_sizes, int n_in,
                              void* d_out, int out_size, void* d_ws, size_t ws_size,
                              hipStream_t stream) {
  (void)in_sizes; (void)n_in; (void)out_size; (void)ws_size;
  const float* feat  = (const float*)d_in[0];
  const float* ipW   = (const float*)d_in[1];
  const float* ipB   = (const float*)d_in[2];
  const float* convW = (const float*)d_in[3];
  const float* convB = (const float*)d_in[4];
  const float* embW  = (const float*)d_in[5];
  const float* embB  = (const float*)d_in[6];
  const float* lng   = (const float*)d_in[7];
  const float* lnb   = (const float*)d_in[8];
  const float* gain  = (const float*)d_in[9];
  float* h   = (float*)d_out;          // h lives in d_out (f32), emb runs in place
  float* stg = (float*)d_ws;           // f32 pooled staging, max 16.8 MB

  k_inproj<<<(TOTAL + 127)/128, 256, 0, stream>>>(feat, ipW, ipB, h);

  for (int d = 9; d >= 5; --d){
    int L = d - 1;
    int Np = 1 << (2*L);
    k_pool<<<(Np*16 + 255)/256, 256, 0, stream>>>(h, stg, Np, OFFS[L], OFFS[d]);
    k_conv<<<Np/64, 256, 0, stream>>>(stg, convW + (size_t)L*36864,
        convB + (size_t)L*64, h, Np, OFFS[L], L);
  }

  // d=4..1 fused single-block tail
  k_tail<<<1, 256, 0, stream>>>(h, convW, convB);

  k_emb<<<2734, 256, 0, stream>>>(h, embW, embB, lng, lnb, gain);
}

// Round 7
// 347.744 us; speedup vs baseline: 6.1269x; 1.2417x over previous
//
#include <hip/hip_runtime.h>
#include <hip/hip_bf16.h>

static constexpr int TOTAL = 349525;
static constexpr int OFFS[11] = {0,1,5,21,85,341,1365,5461,21845,87381,349525};
// emb blocks of 128 nodes per level: counts {1,1,1,1,2,8,32,128,512,2048}
static constexpr int EBLK[11] = {0,1,2,3,4,6,14,46,174,686,2734};

__device__ __forceinline__ unsigned deint(unsigned v){
  v &= 0x55555555u;
  v = (v | (v>>1)) & 0x33333333u;
  v = (v | (v>>2)) & 0x0F0F0F0Fu;
  v = (v | (v>>4)) & 0x00FF00FFu;
  v = (v | (v>>8)) & 0x0000FFFFu;
  return v;
}
__device__ __forceinline__ unsigned ileave(unsigned v){
  v &= 0xFFFFu;
  v = (v | (v<<8)) & 0x00FF00FFu;
  v = (v | (v<<4)) & 0x0F0F0F0Fu;
  v = (v | (v<<2)) & 0x33333333u;
  v = (v | (v<<1)) & 0x55555555u;
  return v;
}

// ---------- in_proj: h[g] = concat(f, posenc) @ W(40x64) + b ----------
__global__ __launch_bounds__(256) void k_inproj(const float* __restrict__ feat,
    const float* __restrict__ W, const float* __restrict__ B, float* __restrict__ h){
  __shared__ float Alt[128][44];   // [node][k], pitch 44
  __shared__ float Wl[40][68];     // [k][ch], rows 16B-aligned
  int t = threadIdx.x;
  int base = blockIdx.x * 128;
  for (int idx = t; idx < 40*64; idx += 256)
    Wl[idx >> 6][idx & 63] = W[idx];
  if (t < 128){
    int g = base + t;
    float* row = Alt[t];
    if (g < TOTAL){
      int d = 0;
      #pragma unroll
      for (int i = 1; i <= 9; ++i) if (g >= OFFS[i]) d = i;
      int local = g - OFFS[d];
      unsigned ix = deint((unsigned)local), iy = deint(((unsigned)local) >> 1);
      float inv = 1.0f / (float)(1 << d);
      float px = ((float)ix + 0.5f) * inv;
      float py = ((float)iy + 0.5f) * inv;
      float pd = (float)d * (1.0f/9.0f);
      row[0] = feat[g]; row[1] = px; row[2] = py; row[3] = pd;
      float p3[3] = {px, py, pd};
      #pragma unroll
      for (int c = 0; c < 3; ++c){
        float s, co;
        __sincosf(6.28318530717958647692f * p3[c], &s, &co);
        float* rb = row + 4 + c*12;
        #pragma unroll
        for (int f = 0; f < 6; ++f){
          rb[f] = s; rb[6+f] = co;
          float s2 = 2.f*s*co, c2 = 1.f - 2.f*s*s;
          s = s2; co = c2;
        }
      }
    } else {
      #pragma unroll
      for (int k = 0; k < 40; ++k) row[k] = 0.f;
    }
  }
  __syncthreads();
  int tr = t >> 3, tc = t & 7;        // 4 nodes x 8 ch
  float acc[4][8];
  #pragma unroll
  for (int i=0;i<4;++i)
    #pragma unroll
    for (int c=0;c<8;++c) acc[i][c] = 0.f;
  #pragma unroll 2
  for (int k4 = 0; k4 < 10; ++k4){
    float av4[4][4];
    #pragma unroll
    for (int i=0;i<4;++i){
      float4 aa = *(const float4*)&Alt[tr*4+i][k4*4];
      av4[i][0]=aa.x; av4[i][1]=aa.y; av4[i][2]=aa.z; av4[i][3]=aa.w;
    }
    #pragma unroll
    for (int j=0;j<4;++j){
      float4 lo = *(const float4*)&Wl[k4*4+j][tc*8];
      float4 hi = *(const float4*)&Wl[k4*4+j][tc*8+4];
      float wv[8];
      wv[0]=lo.x; wv[1]=lo.y; wv[2]=lo.z; wv[3]=lo.w;
      wv[4]=hi.x; wv[5]=hi.y; wv[6]=hi.z; wv[7]=hi.w;
      #pragma unroll
      for (int i=0;i<4;++i){
        float a = av4[i][j];
        #pragma unroll
        for (int c=0;c<8;++c) acc[i][c] += a*wv[c];
      }
    }
  }
  #pragma unroll
  for (int i=0;i<4;++i){
    int g = base + tr*4 + i;
    if (g >= TOTAL) continue;
    float ov[8];
    #pragma unroll
    for (int c=0;c<8;++c) ov[c] = acc[i][c] + B[tc*8+c];
    float* dst = &h[(size_t)g*64 + tc*8];
    *(float4*)dst       = *(const float4*)&ov[0];
    *(float4*)(dst + 4) = *(const float4*)&ov[4];
  }
}

// ---------- conv (halo, fused pool): h[L] = relu( gather9(pool(h)) @ W + b ) ----------
// Block = 64 Morton nodes = 8x8 tile; halo 10x10 pooled rows staged ONCE.
// Pool fused into halo staging: pooled = 0.25*sum(children, h[L+1]) + parent (h[L]).
__global__ __launch_bounds__(256) void k_conv(float* __restrict__ h,
    const float* __restrict__ W, const float* __restrict__ Bb,
    int N, int offL, int offC, int lbits){
  __shared__ float halo[100][68];   // [halo row][kk], pitch 68
  __shared__ float Wl[64][68];      // [kk][ch]
  __shared__ int hkey[100];
  int t = threadIdx.x;
  int nb = blockIdx.x * 64;
  int res = 1 << lbits;
  if (t < 100){
    int i = t % 10, j = t / 10;
    int gx = (int)deint((unsigned)nb) - 1 + i;
    int gy = (int)deint(((unsigned)nb) >> 1) - 1 + j;
    bool ok = (gx >= 0 && gy >= 0 && gx < res && gy < res);
    hkey[t] = ok ? (int)(ileave((unsigned)gx) | (ileave((unsigned)gy) << 1)) : -1;
  }
  __syncthreads();
  // stage halo: pooled rows (fused pool), 1600 float4s
  const float* hP = h + (size_t)offL * 64;   // parent level L
  const float* hC = h + (size_t)offC * 64;   // child level L+1
  for (int e = t; e < 1600; e += 256){
    int hi = e >> 4, u = e & 15;
    int key = hkey[hi];
    float4 r = make_float4(0.f,0.f,0.f,0.f);
    if (key >= 0){
      const float4* c = (const float4*)(hC + (size_t)(4*key)*64) + u;
      float4 c0 = c[0], c1 = c[16], c2 = c[32], c3 = c[48];
      float4 pr = *((const float4*)(hP + (size_t)key*64) + u);
      r.x = 0.25f*(c0.x+c1.x+c2.x+c3.x) + pr.x;
      r.y = 0.25f*(c0.y+c1.y+c2.y+c3.y) + pr.y;
      r.z = 0.25f*(c0.z+c1.z+c2.z+c3.z) + pr.z;
      r.w = 0.25f*(c0.w+c1.w+c2.w+c3.w) + pr.w;
    }
    *(float4*)&halo[hi][u*4] = r;
  }
  // W m=0 prefetch (NAMED regs only — arrays here go to scratch, round-6 lesson)
  float4 rW0, rW1, rW2, rW3;
  {
    const float4* W4 = (const float4*)W;
    rW0 = W4[t*4]; rW1 = W4[t*4+1]; rW2 = W4[t*4+2]; rW3 = W4[t*4+3];
  }
  int tr = t >> 3, tc = t & 7;       // 2 nodes x 8 ch per thread
  int n0 = tr*2, n1 = tr*2 + 1;
  int lx0 = (int)deint((unsigned)n0), ly0 = (int)deint(((unsigned)n0) >> 1);
  int lx1 = (int)deint((unsigned)n1), ly1 = (int)deint(((unsigned)n1) >> 1);
  float acc[2][8];
  #pragma unroll
  for (int i=0;i<2;++i)
    #pragma unroll
    for (int c=0;c<8;++c) acc[i][c] = 0.f;

  for (int m=0;m<9;++m){
    __syncthreads();                 // halo staged (m=0) / prev compute done with Wl
    {
      int kk = t >> 2, c0 = (t & 3)*16;
      *(float4*)&Wl[kk][c0]      = rW0;
      *(float4*)&Wl[kk][c0 + 4]  = rW1;
      *(float4*)&Wl[kk][c0 + 8]  = rW2;
      *(float4*)&Wl[kk][c0 + 12] = rW3;
    }
    if (m < 8){
      const float4* W4 = (const float4*)(W + (size_t)(m+1)*4096);
      rW0 = W4[t*4]; rW1 = W4[t*4+1]; rW2 = W4[t*4+2]; rW3 = W4[t*4+3];
    }
    __syncthreads();
    int r0 = (ly0 + m/3)*10 + lx0 + m%3;   // (ly+dy+1)*10 + (lx+dx+1)
    int r1 = (ly1 + m/3)*10 + lx1 + m%3;
    #pragma unroll 2
    for (int k4=0;k4<16;++k4){
      float4 a0 = *(const float4*)&halo[r0][k4*4];
      float4 a1 = *(const float4*)&halo[r1][k4*4];
      float av0[4] = {a0.x, a0.y, a0.z, a0.w};
      float av1[4] = {a1.x, a1.y, a1.z, a1.w};
      #pragma unroll
      for (int j=0;j<4;++j){
        float4 lo = *(const float4*)&Wl[k4*4+j][tc*8];
        float4 hi = *(const float4*)&Wl[k4*4+j][tc*8+4];
        float wv[8];
        wv[0]=lo.x; wv[1]=lo.y; wv[2]=lo.z; wv[3]=lo.w;
        wv[4]=hi.x; wv[5]=hi.y; wv[6]=hi.z; wv[7]=hi.w;
        #pragma unroll
        for (int c=0;c<8;++c){
          acc[0][c] += av0[j]*wv[c];
          acc[1][c] += av1[j]*wv[c];
        }
      }
    }
  }
  float* hO = h + (size_t)offL * 64;
  #pragma unroll
  for (int i=0;i<2;++i){
    int node = nb + tr*2 + i;
    if (node >= N) continue;
    float ov[8];
    #pragma unroll
    for (int c=0;c<8;++c){
      float v = acc[i][c] + Bb[tc*8+c];
      ov[c] = v > 0.f ? v : 0.f;
    }
    float* dst = &hO[(size_t)node*64 + tc*8];
    *(float4*)dst       = *(const float4*)&ov[0];
    *(float4*)(dst + 4) = *(const float4*)&ov[4];
  }
}

// ---------- fused tail: d=4..1, one block; Pt + zero-row; Wl staged per m ----------
__global__ __launch_bounds__(256) void k_tail(float* __restrict__ h,
    const float* __restrict__ convW, const float* __restrict__ convB){
  __shared__ float Pt[65][68];    // row 64 = zero row for invalid neighbors
  __shared__ float Wl[64][68];
  int t = threadIdx.x;
  #pragma unroll
  for (int d = 4; d >= 1; --d){
    const int L = d - 1;
    const int Np = 1 << (2*L);   // 64,16,4,1
    for (int e = t; e < Np*16; e += 256){
      int node = e >> 4, u = e & 15;
      const float4* c = (const float4*)(h + (size_t)(OFFS[d] + 4*node)*64) + u;
      float4 c0 = c[0], c1 = c[16], c2 = c[32], c3 = c[48];
      float4 pr = *((const float4*)(h + (size_t)(OFFS[L] + node)*64) + u);
      float4 r;
      r.x = 0.25f*(c0.x+c1.x+c2.x+c3.x) + pr.x;
      r.y = 0.25f*(c0.y+c1.y+c2.y+c3.y) + pr.y;
      r.z = 0.25f*(c0.z+c1.z+c2.z+c3.z) + pr.z;
      r.w = 0.25f*(c0.w+c1.w+c2.w+c3.w) + pr.w;
      *(float4*)&Pt[node][u*4] = r;
    }
    if (t < 17) *(float4*)&Pt[64][t*4] = make_float4(0.f,0.f,0.f,0.f);
    __syncthreads();
    if (L == 0){
      if (t < 16) ((float4*)h)[t] = *(const float4*)&Pt[0][t*4];
      break;
    }
    const int R = (L == 3) ? 2 : 1;
    const int res = 1 << L;
    int tr = t >> 3, tc = t & 7;
    bool act = (tr*R) < Np;
    float acc[2][8];
    #pragma unroll
    for (int i=0;i<2;++i)
      #pragma unroll
      for (int c=0;c<8;++c) acc[i][c] = 0.f;
    unsigned ixs[2] = {0,0}, iys[2] = {0,0};
    if (act){
      #pragma unroll
      for (int i=0;i<R;++i){
        unsigned node = (unsigned)(tr*R + i);
        ixs[i] = deint(node); iys[i] = deint(node >> 1);
      }
    }
    const float* WL = convW + (size_t)L*36864;
    float4 rW0, rW1, rW2, rW3;
    {
      const float4* W4 = (const float4*)WL;
      rW0 = W4[t*4]; rW1 = W4[t*4+1]; rW2 = W4[t*4+2]; rW3 = W4[t*4+3];
    }
    for (int m=0;m<9;++m){
      __syncthreads();               // prev compute done reading Wl
      {
        int kk = t >> 2, c0 = (t & 3)*16;
        *(float4*)&Wl[kk][c0]      = rW0;
        *(float4*)&Wl[kk][c0 + 4]  = rW1;
        *(float4*)&Wl[kk][c0 + 8]  = rW2;
        *(float4*)&Wl[kk][c0 + 12] = rW3;
      }
      if (m < 8){
        const float4* W4 = (const float4*)(WL + (size_t)(m+1)*4096);
        rW0 = W4[t*4]; rW1 = W4[t*4+1]; rW2 = W4[t*4+2]; rW3 = W4[t*4+3];
      }
      __syncthreads();
      if (act){
        int dy = m/3 - 1, dx = m%3 - 1;
        int key[2];
        #pragma unroll
        for (int i=0;i<R;++i){
          int nx = (int)ixs[i] + dx, ny = (int)iys[i] + dy;
          key[i] = (nx>=0 && ny>=0 && nx<res && ny<res)
                 ? (int)(ileave((unsigned)nx) | (ileave((unsigned)ny) << 1)) : 64;
        }
        #pragma unroll 2
        for (int k4=0;k4<16;++k4){
          float av4[2][4];
          #pragma unroll
          for (int i=0;i<R;++i){
            float4 aa = *(const float4*)&Pt[key[i]][k4*4];
            av4[i][0]=aa.x; av4[i][1]=aa.y; av4[i][2]=aa.z; av4[i][3]=aa.w;
          }
          #pragma unroll
          for (int j=0;j<4;++j){
            float4 lo = *(const float4*)&Wl[k4*4+j][tc*8];
            float4 hi = *(const float4*)&Wl[k4*4+j][tc*8+4];
            float wv[8];
            wv[0]=lo.x; wv[1]=lo.y; wv[2]=lo.z; wv[3]=lo.w;
            wv[4]=hi.x; wv[5]=hi.y; wv[6]=hi.z; wv[7]=hi.w;
            #pragma unroll
            for (int i=0;i<R;++i){
              float a = av4[i][j];
              #pragma unroll
              for (int c=0;c<8;++c) acc[i][c] += a*wv[c];
            }
          }
        }
      }
    }
    __syncthreads();   // all Pt/Wl reads done before h stores / next level
    if (act){
      #pragma unroll
      for (int i=0;i<R;++i){
        int node = tr*R + i;
        float ov[8];
        #pragma unroll
        for (int c=0;c<8;++c){
          float v = acc[i][c] + convB[L*64 + tc*8 + c];
          ov[c] = v > 0.f ? v : 0.f;
        }
        float* dst = &h[(size_t)(OFFS[L] + node)*64 + tc*8];
        *(float4*)dst       = *(const float4*)&ov[0];
        *(float4*)(dst + 4) = *(const float4*)&ov[4];
      }
    }
    __syncthreads();
  }
}

// ---------- emb + layernorm + gain, in place over h ----------
__global__ __launch_bounds__(256) void k_emb(float* h, const float* __restrict__ embW,
    const float* __restrict__ embB, const float* __restrict__ lng,
    const float* __restrict__ lnb, const float* __restrict__ gain){
  int bb = blockIdx.x;
  int d = 0;
  #pragma unroll
  for (int i = 1; i <= 9; ++i) if (bb >= EBLK[i]) d = i;
  int nb = (bb - EBLK[d]) * 128;
  int N = 1 << (2*d);
  int off = OFFS[d];

  __shared__ float Alt[128][68];   // [node][k]
  __shared__ float Wl[64][68];     // [k][ch]
  int t = threadIdx.x;
  #pragma unroll
  for (int j=0;j<8;++j){
    int e = t + j*256;
    int node = e >> 4, u = e & 15;
    int g = nb + node;
    float4 v = (g < N) ? *((const float4*)(h + (size_t)(off + g)*64) + u)
                       : make_float4(0.f,0.f,0.f,0.f);
    *(float4*)&Alt[node][u*4] = v;
  }
  const float* Wd = embW + (size_t)d*4096;
  for (int idx = t; idx < 4096; idx += 256)
    Wl[idx >> 6][idx & 63] = Wd[idx];
  __syncthreads();
  int tr = t >> 3, tc = t & 7;
  float acc[4][8];
  #pragma unroll
  for (int c=0;c<8;++c){
    float bv = embB[d*64 + tc*8 + c];
    #pragma unroll
    for (int i=0;i<4;++i) acc[i][c] = bv;
  }
  #pragma unroll 2
  for (int k4=0;k4<16;++k4){
    float av4[4][4];
    #pragma unroll
    for (int i=0;i<4;++i){
      float4 aa = *(const float4*)&Alt[tr*4+i][k4*4];
      av4[i][0]=aa.x; av4[i][1]=aa.y; av4[i][2]=aa.z; av4[i][3]=aa.w;
    }
    #pragma unroll
    for (int j=0;j<4;++j){
      float4 lo = *(const float4*)&Wl[k4*4+j][tc*8];
      float4 hi = *(const float4*)&Wl[k4*4+j][tc*8+4];
      float wv[8];
      wv[0]=lo.x; wv[1]=lo.y; wv[2]=lo.z; wv[3]=lo.w;
      wv[4]=hi.x; wv[5]=hi.y; wv[6]=hi.z; wv[7]=hi.w;
      #pragma unroll
      for (int i=0;i<4;++i){
        float a = av4[i][j];
        #pragma unroll
        for (int c=0;c<8;++c) acc[i][c] += a*wv[c];
      }
    }
  }
  float gvals[8], bvals[8];
  #pragma unroll
  for (int c=0;c<8;++c){
    gvals[c] = lng[d*64 + tc*8 + c];
    bvals[c] = lnb[d*64 + tc*8 + c];
  }
  float gn = gain[d];
  #pragma unroll
  for (int i=0;i<4;++i){
    float s = 0.f, q = 0.f;
    #pragma unroll
    for (int c=0;c<8;++c){ s += acc[i][c]; q += acc[i][c]*acc[i][c]; }
    #pragma unroll
    for (int msk = 1; msk < 8; msk <<= 1){
      s += __shfl_xor(s, msk, 64);
      q += __shfl_xor(q, msk, 64);
    }
    float mu = s * 0.015625f;
    float var = q * 0.015625f - mu*mu;
    float rs = rsqrtf(var + 1e-5f);
    int node = nb + tr*4 + i;
    if (node < N){
      float ov[8];
      #pragma unroll
      for (int c=0;c<8;++c)
        ov[c] = ((acc[i][c] - mu) * rs * gvals[c] + bvals[c]) * gn;
      float* dst = &h[(size_t)(off + node)*64 + tc*8];
      *(float4*)dst       = *(const float4*)&ov[0];
      *(float4*)(dst + 4) = *(const float4*)&ov[4];
    }
  }
}

extern "C" void kernel_launch(void* const* d_in, const int* in_sizes, int n_in,
                              void* d_out, int out_size, void* d_ws, size_t ws_size,
                              hipStream_t stream) {
  (void)in_sizes; (void)n_in; (void)out_size; (void)d_ws; (void)ws_size;
  const float* feat  = (const float*)d_in[0];
  const float* ipW   = (const float*)d_in[1];
  const float* ipB   = (const float*)d_in[2];
  const float* convW = (const float*)d_in[3];
  const float* convB = (const float*)d_in[4];
  const float* embW  = (const float*)d_in[5];
  const float* embB  = (const float*)d_in[6];
  const float* lng   = (const float*)d_in[7];
  const float* lnb   = (const float*)d_in[8];
  const float* gain  = (const float*)d_in[9];
  float* h = (float*)d_out;            // h lives in d_out (f32), emb runs in place

  k_inproj<<<(TOTAL + 127)/128, 256, 0, stream>>>(feat, ipW, ipB, h);

  // levels L=8..4: halo conv with fused pool (reads h[L+1] + h[L], writes h[L])
  for (int L = 8; L >= 4; --L){
    int Np = 1 << (2*L);
    k_conv<<<Np/64, 256, 0, stream>>>(h, convW + (size_t)L*36864,
        convB + (size_t)L*64, Np, OFFS[L], OFFS[L+1], L);
  }

  // d=4..1 fused single-block tail
  k_tail<<<1, 256, 0, stream>>>(h, convW, convB);

  k_emb<<<2734, 256, 0, stream>>>(h, embW, embB, lng, lnb, gain);
}